// Round 14
// baseline (1603.238 us; speedup 1.0000x reference)
//
#include <hip/hip_runtime.h>

// ConvLSTM2D (B=16,T=5,H=W=256,Cin=3,F=8) + BN + LeakyReLU + Dense(8->2)
// FUSED-5 v3. r13 proved dispatch boundaries are structurally ~40us (cross-XCD
// L2 flush for the recurrence hand-off + cold-cache latency-bound restart), so
// single-dispatch (r12 chassis) is right; its limits were 2 waves/SIMD and
// strip waste. r14: tile 24x24 / region 32x32 -> TWO exact 16px strips (no
// column waste, 1.78x compute ratio), LDS 46.2KB -> 3 blocks/CU (12 waves),
// h-weight-lo MFMAs dropped (r8-validated error algebra: ~1e-4, 10x under the
// fp16-h-storage noise floor), and x staging software-pipelined (t+1 global
// loads in flight during step t compute). h ping-pong in LDS w/ zero ring +
// out-of-image masking (r11); c in registers; epilogue fused into t=4.

#define BB  16
#define TT  5
#define HH  256
#define WW  256
#define CIN 3
#define FF  8
#define GG  32

#define TWO 24     // output tile width/height
#define LWW 34     // LDS width  (32 region + zero ring)
#define LHH 34     // LDS height
#define NRW 8      // region rows per wave (32/4)
#define NSTG 5     // staging slots/thread: ceil(34*34/256)
#define XSTR (HH * WW * CIN)   // x element stride per timestep

#define LOG2E 1.44269504088896340736f

typedef _Float16 half8  __attribute__((ext_vector_type(8)));
typedef _Float16 half4  __attribute__((ext_vector_type(4)));
typedef float    floatx4 __attribute__((ext_vector_type(4)));

__device__ __forceinline__ float frcp(float x) { return __builtin_amdgcn_rcpf(x); }
__device__ __forceinline__ float sig2(float z)  { return frcp(1.0f + __builtin_amdgcn_exp2f(z)); }
__device__ __forceinline__ float tanh2(float z) { return 1.0f - 2.0f * frcp(1.0f + __builtin_amdgcn_exp2f(z)); }

#define MFMA(A, B, C) __builtin_amdgcn_mfma_f32_16x16x32_f16((A), (B), (C), 0, 0, 0)

// ---------------------------------------------------------------------------
// 10 hi-only B-fragments, activation scale folded per column
// (i,f,o: -log2e; g: +2log2e). B layout: n = lane&15, k = quad*8+j.
// K-chunks: 0: x taps0-7 (k=tap*4+ci); 1: x tap8 (k=ci);
//           2..4: h taps [4c..4c+3] (k=(tap-4c)*8+ci), taps>8 zero.
// ---------------------------------------------------------------------------
__global__ void build_frags(const float* __restrict__ wk,
                            const float* __restrict__ wr,
                            _Float16* __restrict__ blob) {
    const int lane = threadIdx.x & 63;
    const int quad = lane >> 4, nlo = lane & 15;
    for (int chunk = 0; chunk < 5; ++chunk) {
        for (int nh = 0; nh < 2; ++nh) {
            const int n = nh * 16 + nlo;
            const float scale = (n >= 16 && n < 24) ? (2.0f * LOG2E) : (-LOG2E);
            _Float16* dhi = blob + ((size_t)(chunk * 2 + nh) * 64 + lane) * 8;
            for (int j = 0; j < 8; ++j) {
                const int k = quad * 8 + j;
                float w = 0.0f;
                if (chunk == 0) {
                    int tap = k >> 2, ci = k & 3;
                    if (ci < 3) w = wk[(tap * 3 + ci) * GG + n];
                } else if (chunk == 1) {
                    if (quad == 0 && j < 3) w = wk[(8 * 3 + j) * GG + n];
                } else {
                    int c = chunk - 2;
                    int tap = c * 4 + quad, ci = j;
                    if (tap < 9) w = wr[(tap * FF + ci) * GG + n];
                }
                dhi[j] = (_Float16)(w * scale);
            }
        }
    }
}

// ---------------------------------------------------------------------------
// Fused ConvLSTM: grid (11,11,16) x 256 thr; block = 24x24 output tile,
// all 5 timesteps over its 32x32 region. 3 blocks/CU (LDS 46240).
// ---------------------------------------------------------------------------
__global__ __launch_bounds__(256, 3) void lstm_fused(
    const float* __restrict__ xg,       // [B,T,H,W,3] fp32
    const _Float16* __restrict__ blob,  // 10 scaled B-fragments
    const float* __restrict__ bias,
    const float* __restrict__ gamma, const float* __restrict__ beta,
    const float* __restrict__ mean,  const float* __restrict__ var,
    const float* __restrict__ dw,    const float* __restrict__ db,
    float* __restrict__ out)            // [B,H,W,2]
{
    __shared__ half8 hAs[LHH * LWW];   // h ping (18,496 B)
    __shared__ half8 hBs[LHH * LWW];   // h pong
    __shared__ half4 xls[LHH * LWW];   // x tile (3ch + pad), pipelined restage

    const int tid  = threadIdx.x;
    const int bx = blockIdx.x, by = blockIdx.y, b = blockIdx.z;
    const int lane = tid & 63, wave = tid >> 6;
    const int quad = lane >> 4, nlo = lane & 15;
    const bool lo8 = (nlo < 8);
    const int fc = nlo & 7;
    const int m0 = quad * 4 + (lo8 ? 0 : 2);   // strip-local pixel (of 2)

    // lane-constant LDS tap offsets
    const int xt0 = 2 * quad, xt1 = xt0 + 1;
    const int xoff0 = (xt0 / 3) * LWW + (xt0 % 3);
    const int xoff1 = (xt1 / 3) * LWW + (xt1 % 3);
    const int xoff2 = 2 * LWW + 2;
    int hoff[3];
#pragma unroll
    for (int c = 0; c < 3; ++c) {
        int tap = c * 4 + quad;
        if (tap > 8) tap = 8;                   // padded taps: B rows zero
        hoff[c] = (tap / 3) * LWW + (tap % 3);
    }

    // B-fragments resident
    half8 bfh[10];
#pragma unroll
    for (int i = 0; i < 10; ++i)
        bfh[i] = *(const half8*)(blob + ((size_t)i * 64 + lane) * 8);

    const float bv0 = bias[nlo] * (-LOG2E);
    const float bv1 = bias[16 + nlo] * (lo8 ? 2.0f * LOG2E : -LOG2E);

    const float bn_s = gamma[fc] * rsqrtf(var[fc] + 1e-3f);
    const float bn_b = beta[fc] - mean[fc] * bn_s;
    const float dw0 = dw[fc * 2 + 0], dw1 = dw[fc * 2 + 1];
    const float db0 = db[0], db1 = db[1];

    // zero both h buffers (ring stays zero; interior fully rewritten per step)
    const half8 hz = {(_Float16)0, (_Float16)0, (_Float16)0, (_Float16)0,
                      (_Float16)0, (_Float16)0, (_Float16)0, (_Float16)0};
    for (int l = tid; l < LHH * LWW; l += 256) { hAs[l] = hz; hBs[l] = hz; }

    // c state in registers: 8 rows x 2 strips x 2 px
    float c0r[NRW][2], c1r[NRW][2];
#pragma unroll
    for (int r = 0; r < NRW; ++r) { c0r[r][0] = c0r[r][1] = 0.f;
                                    c1r[r][0] = c1r[r][1] = 0.f; }

    // ---- x staging slot geometry (t-invariant) ----
    int  xgo[NSTG];     // global element offset at t=0 (valid slots only)
    bool xgv[NSTG];     // slot maps to an in-image pixel
#pragma unroll
    for (int k = 0; k < NSTG; ++k) {
        const int l = tid + k * 256;
        int rr = l / LWW, rc = l - rr * LWW;
        int iy = by * TWO + rr - 5, ix = bx * TWO + rc - 5;
        const bool ok = (l < LHH * LWW) && (unsigned)iy < HH && (unsigned)ix < WW;
        xgv[k] = ok;
        xgo[k] = ok ? ((b * TT * HH + iy) * WW + ix) * CIN : 0;
    }

    // prefetch + stage x(0)
    float xr[NSTG][3];
#pragma unroll
    for (int k = 0; k < NSTG; ++k) {
        xr[k][0] = xgv[k] ? xg[xgo[k] + 0] : 0.f;
        xr[k][1] = xgv[k] ? xg[xgo[k] + 1] : 0.f;
        xr[k][2] = xgv[k] ? xg[xgo[k] + 2] : 0.f;
    }
#pragma unroll
    for (int k = 0; k < NSTG; ++k) {
        const int l = tid + k * 256;
        if (l < LHH * LWW) {
            half4 vh; vh.x = (_Float16)xr[k][0]; vh.y = (_Float16)xr[k][1];
            vh.z = (_Float16)xr[k][2]; vh.w = (_Float16)0;
            xls[l] = vh;
        }
    }
    __syncthreads();

    for (int t = 0; t < TT; ++t) {
        // issue x(t+1) global loads now; they complete during compute
        if (t < TT - 1) {
            const int toff = (t + 1) * XSTR;
#pragma unroll
            for (int k = 0; k < NSTG; ++k) {
                xr[k][0] = xgv[k] ? xg[xgo[k] + toff + 0] : 0.f;
                xr[k][1] = xgv[k] ? xg[xgo[k] + toff + 1] : 0.f;
                xr[k][2] = xgv[k] ? xg[xgo[k] + toff + 2] : 0.f;
            }
        }

        half8* hRd = (t & 1) ? hBs : hAs;
        half8* hWr = (t & 1) ? hAs : hBs;

#pragma unroll
        for (int r = 0; r < NRW; ++r) {
            const int row = wave * NRW + r;          // region row 0..31
            const int rowbase = row * LWW + nlo;

            // batch LDS loads for both strips
            half4 xp[2], xq[2], xs_[2];
            half8 ah[2][3];
#pragma unroll
            for (int st = 0; st < 2; ++st) {
                const int base = rowbase + st * 16;
                xp[st]  = xls[base + xoff0];
                xq[st]  = xls[base + xoff1];
                xs_[st] = xls[base + xoff2];
                if (t > 0) {
#pragma unroll
                    for (int c = 0; c < 3; ++c)
                        ah[st][c] = hRd[base + hoff[c]];
                }
            }

#pragma unroll
            for (int st = 0; st < 2; ++st) {
                const int gx0 = st * 16;             // strip origin (region col)

                half8 a_xA = (half8){xp[st].x, xp[st].y, xp[st].z, xp[st].w,
                                     xq[st].x, xq[st].y, xq[st].z, xq[st].w};
                half8 a_xB = (half8){xs_[st].x, xs_[st].y, xs_[st].z, xs_[st].w,
                                     xs_[st].x, xs_[st].y, xs_[st].z, xs_[st].w};

                floatx4 acc0 = {bv0, bv0, bv0, bv0};
                floatx4 acc1 = {bv1, bv1, bv1, bv1};
                acc0 = MFMA(a_xA, bfh[0], acc0);  acc1 = MFMA(a_xA, bfh[1], acc1);
                acc0 = MFMA(a_xB, bfh[2], acc0);  acc1 = MFMA(a_xB, bfh[3], acc1);
                if (t > 0) {
#pragma unroll
                    for (int c = 0; c < 3; ++c) {
                        acc0 = MFMA(ah[st][c], bfh[4 + c * 2], acc0);
                        acc1 = MFMA(ah[st][c], bfh[5 + c * 2], acc1);
                    }
                }

                // gate phase (C layout: px m=quad*4+reg, ch=nlo / nlo+16)
                float s0 = lo8 ? acc0[2] : acc0[0]; float r0 = __shfl_xor(s0, 8, 64);
                float s1 = lo8 ? acc0[3] : acc0[1]; float r1 = __shfl_xor(s1, 8, 64);
                float s2 = lo8 ? acc1[2] : acc1[0]; float r2 = __shfl_xor(s2, 8, 64);
                float s3 = lo8 ? acc1[3] : acc1[1]; float r3 = __shfl_xor(s3, 8, 64);

                const float zi0 = lo8 ? acc0[0] : r0, zi1 = lo8 ? acc0[1] : r1;
                const float zf0 = lo8 ? r0 : acc0[2], zf1 = lo8 ? r1 : acc0[3];
                const float zg0 = lo8 ? acc1[0] : r2, zg1 = lo8 ? acc1[1] : r3;
                const float zo0 = lo8 ? r2 : acc1[2], zo1 = lo8 ? r3 : acc1[3];

                const float ii0 = sig2(zi0), ff0 = sig2(zf0), gg0 = tanh2(zg0), oo0 = sig2(zo0);
                const float cn0 = ff0 * c0r[r][st] + ii0 * gg0;
                const float hn0 = oo0 * tanh2(cn0 * (2.0f * LOG2E));
                const float ii1 = sig2(zi1), ff1 = sig2(zf1), gg1 = tanh2(zg1), oo1 = sig2(zo1);
                const float cn1 = ff1 * c1r[r][st] + ii1 * gg1;
                const float hn1 = oo1 * tanh2(cn1 * (2.0f * LOG2E));
                c0r[r][st] = cn0; c1r[r][st] = cn1;

                const int pc0 = gx0 + m0;                 // region col of px0
                const int iy  = by * TWO + row - 4;       // image row
                const int ix0 = bx * TWO + pc0 - 4;       // image col of px0

                if (t < TT - 1) {
                    // h -> LDS interior; out-of-image pixels write 0 (SAME pad)
                    const bool iny = (unsigned)iy < HH;
                    const int idx = (row + 1) * LWW + (pc0 + 1);
                    _Float16* hp = (_Float16*)hWr;
                    hp[idx * 8 + fc] =
                        (iny && (unsigned)ix0 < WW) ? (_Float16)hn0 : (_Float16)0;
                    hp[(idx + 1) * 8 + fc] =
                        (iny && (unsigned)(ix0 + 1) < WW) ? (_Float16)hn1 : (_Float16)0;
                } else {
                    // fused epilogue: BN -> LeakyReLU(0.3) -> Dense(8->2)
                    float y0 = bn_s * hn0 + bn_b; y0 = (y0 >= 0.f) ? y0 : 0.3f * y0;
                    float y1 = bn_s * hn1 + bn_b; y1 = (y1 >= 0.f) ? y1 : 0.3f * y1;
                    float p00 = y0 * dw0, p01 = y0 * dw1;
                    float p10 = y1 * dw0, p11 = y1 * dw1;
#pragma unroll
                    for (int m = 1; m <= 4; m <<= 1) {
                        p00 += __shfl_xor(p00, m, 64);
                        p01 += __shfl_xor(p01, m, 64);
                        p10 += __shfl_xor(p10, m, 64);
                        p11 += __shfl_xor(p11, m, 64);
                    }
                    const int j = nlo & 7;
                    if (j < 4) {
                        const int rc = pc0 + (j >> 1);
                        const int k  = j & 1;
                        const int ox = bx * TWO + rc - 4;
                        const int oy = by * TWO + row - 4;
                        // valid cone: region minus 4-ring; clip to image
                        if (rc >= 4 && rc < 28 && row >= 4 && row < 28 &&
                            (unsigned)ox < WW && (unsigned)oy < HH) {
                            float val = (j == 0 ? p00 : j == 1 ? p01 : j == 2 ? p10 : p11)
                                        + (k ? db1 : db0);
                            out[((size_t)(b * HH + oy) * WW + ox) * 2 + k] = val;
                        }
                    }
                }
            }
        }
        __syncthreads();   // xls reads + hWr writes complete
        if (t < TT - 1) {
#pragma unroll
            for (int k = 0; k < NSTG; ++k) {
                const int l = tid + k * 256;
                if (l < LHH * LWW) {
                    half4 vh; vh.x = (_Float16)xr[k][0]; vh.y = (_Float16)xr[k][1];
                    vh.z = (_Float16)xr[k][2]; vh.w = (_Float16)0;
                    xls[l] = vh;
                }
            }
            __syncthreads();   // x(t+1) staged; h(t) visible
        }
    }
}

extern "C" void kernel_launch(void* const* d_in, const int* in_sizes, int n_in,
                              void* d_out, int out_size, void* d_ws, size_t ws_size,
                              hipStream_t stream) {
    const float* x     = (const float*)d_in[0];
    const float* wk    = (const float*)d_in[1];
    const float* wr    = (const float*)d_in[2];
    const float* bias  = (const float*)d_in[3];
    const float* gamma = (const float*)d_in[4];
    const float* beta  = (const float*)d_in[5];
    const float* mean  = (const float*)d_in[6];
    const float* var   = (const float*)d_in[7];
    const float* dw    = (const float*)d_in[8];
    const float* db    = (const float*)d_in[9];
    float* out = (float*)d_out;

    _Float16* blob = (_Float16*)d_ws;   // 10 KB fragment blob

    build_frags<<<1, 64, 0, stream>>>(wk, wr, blob);

    dim3 grid((WW + TWO - 1) / TWO, (HH + TWO - 1) / TWO, BB);  // (11,11,16)
    dim3 block(256);
    lstm_fused<<<grid, block, 0, stream>>>(
        x, blob, bias, gamma, beta, mean, var, dw, db, out);
}